// Round 5
// baseline (280.646 us; speedup 1.0000x reference)
//
#include <hip/hip_runtime.h>
#include <hip/hip_bf16.h>

// ---------------------------------------------------------------------------
// MultiHeadDotProductAttention: rotary + sliding-window (|i-j|<=256) MHA
// B=4 T=2048 E=1024 H=16x64=1024.  bf16 MFMA (16x16x32) for all matmuls.
//
// R5: (a) proj fuses K+V (z=1): one sA staging feeds two B tiles / two acc
//     sets -> staging -17%, barrier-iters -33%;  (b) attn uses 256-row
//     q-blocks with 8 waves -> K/V band refetch 5x -> 3x (-40% HBM);
//     (c) cvt + wtrans fused into one prep dispatch.
//
// Verified layout facts (learn_hip m89/m91/m120):
//   mfma_f32_16x16x32_bf16: A[m=lane&15][k=(lane>>4)*8+j], B[k=...][n=lane&15]
//   C/D: col=lane&15, row=(lane>>4)*4+reg
// ---------------------------------------------------------------------------

typedef __attribute__((ext_vector_type(8))) short s8v;    // 8 x bf16
typedef __attribute__((ext_vector_type(4))) float f4v;    // MFMA acc

#define MFMA_BF16 __builtin_amdgcn_mfma_f32_16x16x32_bf16

#define ASYNC_CP16(g, l)                                             \
  __builtin_amdgcn_global_load_lds(                                  \
      (const __attribute__((address_space(1))) void*)(g),            \
      (__attribute__((address_space(3))) void*)(l), 16, 0, 0)

// swizzled LDS element offset for (row, 16B-granule g) in a [*][64] tile
#define SWZ(row, g) ((row) * 64 + ((((g) ^ ((row) & 7))) * 8))

__device__ __forceinline__ unsigned short f2bf(float f) {
  union { float f; unsigned int u; } v; v.f = f;
  unsigned int r = (v.u + 0x7fffu + ((v.u >> 16) & 1u)) >> 16;  // RNE
  return (unsigned short)r;
}

__device__ __forceinline__ unsigned int pack_bf16(float a, float b) {
  union { __hip_bfloat162 h; unsigned int u; } cv;
  cv.h = __float22bfloat162_rn(make_float2(a, b));
  return cv.u;
}

// ---------------- 1) prep: f32->bf16 casts + weight transposes ---------------
// blocks 0..16383: cvt Xq/Xkv; blocks 16384..20479: wtrans of 4 weights.
__global__ __launch_bounds__(256) void prep_kernel(
    const float* __restrict__ s0, const float* __restrict__ s1,
    unsigned short* __restrict__ d0, unsigned short* __restrict__ d1,
    const float* __restrict__ W0, const float* __restrict__ W1,
    const float* __restrict__ W2, const float* __restrict__ W3,
    unsigned short* __restrict__ D0, unsigned short* __restrict__ D1,
    unsigned short* __restrict__ D2, unsigned short* __restrict__ D3) {
  int g = blockIdx.x;
  if (g < 16384) {
    const float* src = (g < 8192) ? s0 : s1;
    unsigned short* dst = (g < 8192) ? d0 : d1;
    int i = ((g & 8191) * 256 + threadIdx.x) * 4;
    float4 v = *(const float4*)(src + i);
    ushort4 o;
    o.x = f2bf(v.x); o.y = f2bf(v.y); o.z = f2bf(v.z); o.w = f2bf(v.w);
    *(ushort4*)(dst + i) = o;
  } else {
    int w = g - 16384;          // 0..4095
    int z = w >> 10;            // which weight
    int rem = w & 1023;
    const float* W = z == 0 ? W0 : z == 1 ? W1 : z == 2 ? W2 : W3;
    unsigned short* D = z == 0 ? D0 : z == 1 ? D1 : z == 2 ? D2 : D3;
    __shared__ float tile[32][33];
    int n0 = (rem & 31) * 32, k0 = (rem >> 5) * 32;
    int tx = threadIdx.x & 31, ty = threadIdx.x >> 5;  // 32 x 8
#pragma unroll
    for (int r = 0; r < 32; r += 8)
      tile[ty + r][tx] = W[(size_t)(k0 + ty + r) * 1024 + n0 + tx];
    __syncthreads();
#pragma unroll
    for (int r = 0; r < 32; r += 8)
      D[(size_t)(n0 + ty + r) * 1024 + k0 + tx] = f2bf(tile[tx][ty + r]);
  }
}

// ---------------- 2) projection GEMM: z=0 -> Q;  z=1 -> K and V fused -------
// grid (64=m, 8=n, 2=z).  128x128 tile, BK=64; 4 waves x 4x4 MFMA accs
// (x2 acc sets for z=1, sharing the A fragments).
__global__ __launch_bounds__(256) void proj_gemm(
    const unsigned short* __restrict__ XqBf, const unsigned short* __restrict__ XkvBf,
    const unsigned short* __restrict__ Wtq, const unsigned short* __restrict__ Wtk,
    const unsigned short* __restrict__ Wtv,
    unsigned short* __restrict__ Qb, unsigned short* __restrict__ Kb,
    unsigned short* __restrict__ Vt) {
  const int K = 1024;
  int z = blockIdx.z;
  const unsigned short* A   = (z == 0) ? XqBf : XkvBf;
  const unsigned short* Bt0 = (z == 0) ? Wtq : Wtk;

  __shared__ __align__(16) unsigned short sA[128 * 64];
  __shared__ __align__(16) unsigned short sB0[128 * 64];
  __shared__ __align__(16) unsigned short sB1[128 * 64];  // Wtv (z==1 only)

  int tid = threadIdx.x;
  int lane = tid & 63, wave = tid >> 6;
  int quad = lane >> 4, l16 = lane & 15;
  int wm = wave & 1, wn = wave >> 1;
  int m_blk = blockIdx.x * 128, n_blk = blockIdx.y * 128;  // m-major

  f4v acc0[4][4] = {};
  f4v acc1[4][4] = {};
  int srow = tid >> 3, sg = (tid & 7) ^ (srow & 7);
  const unsigned short* gA  = A   + (size_t)(m_blk + srow) * K + sg * 8;
  const unsigned short* gB0 = Bt0 + (size_t)(n_blk + srow) * K + sg * 8;
  const unsigned short* gB1 = Wtv + (size_t)(n_blk + srow) * K + sg * 8;

  for (int k0 = 0; k0 < K; k0 += 64) {
#pragma unroll
    for (int i = 0; i < 4; ++i) {
      ASYNC_CP16(gA + (size_t)i * 32 * K + k0, &sA[i * 2048 + tid * 8]);
      ASYNC_CP16(gB0 + (size_t)i * 32 * K + k0, &sB0[i * 2048 + tid * 8]);
    }
    if (z == 1) {
#pragma unroll
      for (int i = 0; i < 4; ++i)
        ASYNC_CP16(gB1 + (size_t)i * 32 * K + k0, &sB1[i * 2048 + tid * 8]);
    }
    __syncthreads();
#pragma unroll
    for (int ks = 0; ks < 64; ks += 32) {
      s8v af[4], bf0[4];
#pragma unroll
      for (int mt = 0; mt < 4; ++mt)
        af[mt] = *(const s8v*)&sA[SWZ(wm * 64 + mt * 16 + l16, quad + (ks >> 3))];
#pragma unroll
      for (int nt = 0; nt < 4; ++nt)
        bf0[nt] = *(const s8v*)&sB0[SWZ(wn * 64 + nt * 16 + l16, quad + (ks >> 3))];
#pragma unroll
      for (int mt = 0; mt < 4; ++mt)
#pragma unroll
        for (int nt = 0; nt < 4; ++nt)
          acc0[mt][nt] = MFMA_BF16(af[mt], bf0[nt], acc0[mt][nt], 0, 0, 0);
      if (z == 1) {
        s8v bf1[4];
#pragma unroll
        for (int nt = 0; nt < 4; ++nt)
          bf1[nt] = *(const s8v*)&sB1[SWZ(wn * 64 + nt * 16 + l16, quad + (ks >> 3))];
#pragma unroll
        for (int mt = 0; mt < 4; ++mt)
#pragma unroll
          for (int nt = 0; nt < 4; ++nt)
            acc1[mt][nt] = MFMA_BF16(af[mt], bf1[nt], acc1[mt][nt], 0, 0, 0);
      }
    }
    __syncthreads();
  }

  {  // rotary epilogue for Q (z=0, extra 1/8 scale) or K (z=1) -> row-major
    unsigned short* Cb = (z == 0) ? Qb : Kb;
    float post = (z == 0) ? 0.125f : 1.0f;  // fold 1/sqrt(64) into Q (exact)
#pragma unroll
    for (int mt = 0; mt < 4; ++mt)
#pragma unroll
      for (int nt = 0; nt < 4; ++nt)
#pragma unroll
        for (int r = 0; r < 4; ++r) {
          int row = m_blk + wm * 64 + mt * 16 + quad * 4 + r;
          int col = n_blk + wn * 64 + nt * 16 + l16;
          float v = acc0[mt][nt][r];
          float other = __shfl_xor(v, 1);  // pair partner: col^1 == lane^1
          int dh = col & 63;
          int tpos = row & 2047;
          float fi = (float)(dh >> 1) * (1.0f / 32.0f);
          float invf = __expf(-9.210340371976184f * fi);  // 10000^{-i/32}
          float ang = (float)tpos * invf;
          float s, c;
          __sincosf(ang, &s, &c);
          v = (dh & 1) ? (v * c + other * s) : (v * c - other * s);
          Cb[(size_t)row * 1024 + col] = f2bf(v * post);
        }
  }
  if (z == 1) {  // V -> transposed Vt[((b*16+h)*64+dh)][t], pack 4 t's
#pragma unroll
    for (int mt = 0; mt < 4; ++mt)
#pragma unroll
      for (int nt = 0; nt < 4; ++nt) {
        int row0 = m_blk + wm * 64 + mt * 16 + quad * 4;  // t base (mult of 4)
        int col = n_blk + wn * 64 + nt * 16 + l16;        // feature
        int bb = row0 >> 11, t = row0 & 2047;
        int hh = col >> 6, dh = col & 63;
        ushort4 pk;
        pk.x = f2bf(acc1[mt][nt][0]);
        pk.y = f2bf(acc1[mt][nt][1]);
        pk.z = f2bf(acc1[mt][nt][2]);
        pk.w = f2bf(acc1[mt][nt][3]);
        *(ushort4*)&Vt[(((size_t)bb * 16 + hh) * 64 + dh) * 2048 + t] = pk;
      }
  }
}

// ---------------- 3) banded flash attention (S^T, 256-row q-blocks) ---------
// grid (T/256=8, H=16, B=4), 512 threads (8 waves); wave w owns rows
// t0+32w..+31 (2 f-frags).  S^T = K*Q^T: lane l16 = q row.
__global__ __launch_bounds__(512, 2) void attn_kernel(
    const unsigned short* __restrict__ Qb, const unsigned short* __restrict__ Kb,
    const unsigned short* __restrict__ Vt, unsigned short* __restrict__ Ab) {
  const int T = 2048;
  int t0 = blockIdx.x * 256;
  int h = blockIdx.y, b = blockIdx.z;
  int tid = threadIdx.x, lane = tid & 63, wave = tid >> 6;
  int quad = lane >> 4, l16 = lane & 15;

  __shared__ __align__(16) unsigned short sK[64][72];     // [key][d]
  __shared__ __align__(16) unsigned short sV[64][72];     // [d][key]
  __shared__ __align__(16) unsigned short sP[8][16][72];  // [wave][qrow][key]

  size_t base = ((size_t)b * T) * 1024 + (size_t)h * 64;
  size_t vbase = ((size_t)b * 16 + h) * 64 * 2048;
  int qlo = t0 + wave * 32;  // wave-uniform

  // Q B-fragments straight from global (B[k=quad*8+j][n=l16]); Q pre-scaled.
  s8v bq[2][2];
#pragma unroll
  for (int f = 0; f < 2; ++f) {
    const unsigned short* g = Qb + base + (size_t)(qlo + f * 16 + l16) * 1024;
    bq[f][0] = *(const s8v*)(g + quad * 8);
    bq[f][1] = *(const s8v*)(g + 32 + quad * 8);
  }

  f4v oacc[2][4] = {};
  float mrow[2] = {-1e30f, -1e30f}, lrow[2] = {0.0f, 0.0f};

  int kv_lo = max(0, t0 - 256);
  int kv_hi = min(T, t0 + 256 + 256);
  int ntiles = (kv_hi - kv_lo) >> 6;

  // staging with 512 threads: thread -> (row tid>>3, 16B granule tid&7)
  int srow = tid >> 3, sseg = (tid & 7) * 8;
  const unsigned short* gK = Kb + base + (size_t)(kv_lo + srow) * 1024 + sseg;
  const unsigned short* gV = Vt + vbase + (size_t)srow * 2048 + kv_lo + sseg;
  uint4 rk = *(const uint4*)gK;
  uint4 rv = *(const uint4*)gV;

  for (int it = 0; it < ntiles; ++it) {
    int kv0 = kv_lo + (it << 6);
    __syncthreads();  // previous tile's sK/sV reads complete
    *(uint4*)&sK[srow][sseg] = rk;
    *(uint4*)&sV[srow][sseg] = rv;
    __syncthreads();  // sK/sV ready
    if (it + 1 < ntiles) {  // register prefetch overlaps compute
      rk = *(const uint4*)(gK + (size_t)(it + 1) * 64 * 1024);
      rv = *(const uint4*)(gV + (it + 1) * 64);
    }
    // wave-level skip (barriers at loop top -> barrier-safe); every row of an
    // active tile has >=1 unmasked key (64/32 alignment).
    if (kv0 > qlo + 31 + 256 || kv0 + 63 < qlo - 256) continue;

#pragma unroll
    for (int f = 0; f < 2; ++f) {
      int qf = qlo + f * 16;     // wave-uniform
      int qg = qf + l16;         // this lane's q row
      // S^T = K * Q^T : A = K frag (m=key), B = Q frag (n=qrow)
      f4v sacc[4];
#pragma unroll
      for (int nt = 0; nt < 4; ++nt) {
        s8v ak0 = *(const s8v*)&sK[nt * 16 + l16][quad * 8];
        s8v ak1 = *(const s8v*)&sK[nt * 16 + l16][32 + quad * 8];
        f4v zz = {};
        zz = MFMA_BF16(ak0, bq[f][0], zz, 0, 0, 0);
        sacc[nt] = MFMA_BF16(ak1, bq[f][1], zz, 0, 0, 0);
      }
      // mask only when the tile isn't fully inside the band (wave-uniform)
      bool full = (kv0 >= qf - 241) && (kv0 <= qf + 193);
      if (!full) {
#pragma unroll
        for (int nt = 0; nt < 4; ++nt) {
          int kg = kv0 + nt * 16 + quad * 4;
#pragma unroll
          for (int r = 0; r < 4; ++r) {
            int d = qg - (kg + r);
            if (d > 256 || d < -256) sacc[nt][r] = -1e30f;
          }
        }
      }
      // row max: in-lane over 16 + cross-quad (2 shfls)
      float mymax = sacc[0][0];
#pragma unroll
      for (int nt = 0; nt < 4; ++nt)
#pragma unroll
        for (int r = 0; r < 4; ++r) mymax = fmaxf(mymax, sacc[nt][r]);
      mymax = fmaxf(mymax, __shfl_xor(mymax, 16));
      mymax = fmaxf(mymax, __shfl_xor(mymax, 32));

      float mn = fmaxf(mrow[f], mymax);
      float alpha = __expf(mrow[f] - mn);
      mrow[f] = mn;

      float mysum = 0.0f;
#pragma unroll
      for (int nt = 0; nt < 4; ++nt) {
        float e0 = __expf(sacc[nt][0] - mn);
        float e1 = __expf(sacc[nt][1] - mn);
        float e2 = __expf(sacc[nt][2] - mn);
        float e3 = __expf(sacc[nt][3] - mn);
        mysum += (e0 + e1) + (e2 + e3);
        *(uint2*)&sP[wave][l16][nt * 16 + quad * 4] =
            make_uint2(pack_bf16(e0, e1), pack_bf16(e2, e3));
      }
      mysum += __shfl_xor(mysum, 16);
      mysum += __shfl_xor(mysum, 32);
      lrow[f] = lrow[f] * alpha + mysum;

      // P^T B-frags (B[k=key][n=qrow]) from this wave's sP region
      s8v pb0 = *(const s8v*)&sP[wave][l16][quad * 8];
      s8v pb1 = *(const s8v*)&sP[wave][l16][32 + quad * 8];

      // O^T += V^T * P^T : A = V^T frag (m=d), B = P^T
#pragma unroll
      for (int dt = 0; dt < 4; ++dt) {
        s8v av0 = *(const s8v*)&sV[dt * 16 + l16][quad * 8];
        s8v av1 = *(const s8v*)&sV[dt * 16 + l16][32 + quad * 8];
        f4v o = oacc[f][dt];
#pragma unroll
        for (int r = 0; r < 4; ++r) o[r] *= alpha;
        o = MFMA_BF16(av0, pb0, o, 0, 0, 0);
        oacc[f][dt] = MFMA_BF16(av1, pb1, o, 0, 0, 0);
      }
    }
  }

  // normalize + store: O^T C-layout -> lane has q-row l16, d = dt*16+quad*4+r
#pragma unroll
  for (int f = 0; f < 2; ++f) {
    float inv = 1.0f / lrow[f];
    size_t rowoff = base + (size_t)(qlo + f * 16 + l16) * 1024;
#pragma unroll
    for (int dt = 0; dt < 4; ++dt) {
      float o0 = oacc[f][dt][0] * inv, o1 = oacc[f][dt][1] * inv;
      float o2 = oacc[f][dt][2] * inv, o3 = oacc[f][dt][3] * inv;
      *(uint2*)&Ab[rowoff + dt * 16 + quad * 4] =
          make_uint2(pack_bf16(o0, o1), pack_bf16(o2, o3));
    }
  }
}

// ---------------- 4) output GEMM (swizzled, m-major): f32 out ---------------
__global__ __launch_bounds__(256) void out_gemm(
    const unsigned short* __restrict__ A, const unsigned short* __restrict__ Bt,
    float* __restrict__ C) {
  const int K = 1024;
  __shared__ __align__(16) unsigned short sA[128 * 64];
  __shared__ __align__(16) unsigned short sB[128 * 64];

  int tid = threadIdx.x;
  int lane = tid & 63, wave = tid >> 6;
  int quad = lane >> 4, l16 = lane & 15;
  int wm = wave & 1, wn = wave >> 1;
  int m_blk = blockIdx.x * 128, n_blk = blockIdx.y * 128;  // m-major

  f4v acc[4][4] = {};
  int srow = tid >> 3, sg = (tid & 7) ^ (srow & 7);
  const unsigned short* gA = A + (size_t)(m_blk + srow) * K + sg * 8;
  const unsigned short* gB = Bt + (size_t)(n_blk + srow) * K + sg * 8;

  for (int k0 = 0; k0 < K; k0 += 64) {
#pragma unroll
    for (int i = 0; i < 4; ++i) {
      ASYNC_CP16(gA + (size_t)i * 32 * K + k0, &sA[i * 2048 + tid * 8]);
      ASYNC_CP16(gB + (size_t)i * 32 * K + k0, &sB[i * 2048 + tid * 8]);
    }
    __syncthreads();
#pragma unroll
    for (int ks = 0; ks < 64; ks += 32) {
      s8v af[4], bf[4];
#pragma unroll
      for (int mt = 0; mt < 4; ++mt)
        af[mt] = *(const s8v*)&sA[SWZ(wm * 64 + mt * 16 + l16, quad + (ks >> 3))];
#pragma unroll
      for (int nt = 0; nt < 4; ++nt)
        bf[nt] = *(const s8v*)&sB[SWZ(wn * 64 + nt * 16 + l16, quad + (ks >> 3))];
#pragma unroll
      for (int mt = 0; mt < 4; ++mt)
#pragma unroll
        for (int nt = 0; nt < 4; ++nt)
          acc[mt][nt] = MFMA_BF16(af[mt], bf[nt], acc[mt][nt], 0, 0, 0);
    }
    __syncthreads();
  }

#pragma unroll
  for (int mt = 0; mt < 4; ++mt)
#pragma unroll
    for (int nt = 0; nt < 4; ++nt)
#pragma unroll
      for (int r = 0; r < 4; ++r) {
        int row = m_blk + wm * 64 + mt * 16 + quad * 4 + r;
        int col = n_blk + wn * 64 + nt * 16 + l16;
        C[(size_t)row * 1024 + col] = acc[mt][nt][r];
      }
}

// ---------------- launch -----------------------------------------------------
extern "C" void kernel_launch(void* const* d_in, const int* in_sizes, int n_in,
                              void* d_out, int out_size, void* d_ws, size_t ws_size,
                              hipStream_t stream) {
  const float* Xq  = (const float*)d_in[0];
  const float* Xkv = (const float*)d_in[1];
  const float* Wq  = (const float*)d_in[2];
  const float* Wk  = (const float*)d_in[3];
  const float* Wv  = (const float*)d_in[4];
  const float* Wo  = (const float*)d_in[5];
  float* out = (float*)d_out;

  char* ws = (char*)d_ws;
  const size_t MB = 1ull << 20;
  unsigned short* XqBf  = (unsigned short*)(ws + 0 * MB);   // 16 MiB
  unsigned short* XkvBf = (unsigned short*)(ws + 16 * MB);  // 16 MiB
  unsigned short* Wtq   = (unsigned short*)(ws + 32 * MB);  // 2 MiB each
  unsigned short* Wtk   = (unsigned short*)(ws + 34 * MB);
  unsigned short* Wtv   = (unsigned short*)(ws + 36 * MB);
  unsigned short* Wto   = (unsigned short*)(ws + 38 * MB);
  unsigned short* Qb    = (unsigned short*)(ws + 40 * MB);  // 16 MiB
  unsigned short* Kb    = (unsigned short*)(ws + 56 * MB);  // 16 MiB
  unsigned short* Vt    = (unsigned short*)(ws + 72 * MB);  // 16 MiB (transposed V)
  unsigned short* Ab    = XqBf;  // reuse: XqBf dead after proj_gemm

  prep_kernel<<<20480, 256, 0, stream>>>(Xq, Xkv, XqBf, XkvBf,
                                         Wq, Wk, Wv, Wo, Wtq, Wtk, Wtv, Wto);
  proj_gemm<<<dim3(64, 8, 2), 256, 0, stream>>>(XqBf, XkvBf, Wtq, Wtk, Wtv, Qb, Kb, Vt);
  attn_kernel<<<dim3(8, 16, 4), 512, 0, stream>>>(Qb, Kb, Vt, Ab);
  out_gemm<<<dim3(64, 8), 256, 0, stream>>>(Ab, Wto, out);
}

// Round 6
// 250.085 us; speedup vs baseline: 1.1222x; 1.1222x over previous
//
#include <hip/hip_runtime.h>
#include <hip/hip_bf16.h>

// ---------------------------------------------------------------------------
// MultiHeadDotProductAttention: rotary + sliding-window (|i-j|<=256) MHA
// B=4 T=2048 E=1024 H=16x64=1024.  bf16 MFMA (16x16x32) for all matmuls.
//
// R6: revert R5's K+V proj fusion (48KB LDS dropped occupancy 20->11%,
//     proj 71->98us; LDS growth must not cross the blocks/CU boundary).
//     Keep: prep fusion (cvt+wtrans), attn 256-row q-blocks / 8 waves.
//
// Verified layout facts (learn_hip m89/m91/m120):
//   mfma_f32_16x16x32_bf16: A[m=lane&15][k=(lane>>4)*8+j], B[k=...][n=lane&15]
//   C/D: col=lane&15, row=(lane>>4)*4+reg
// ---------------------------------------------------------------------------

typedef __attribute__((ext_vector_type(8))) short s8v;    // 8 x bf16
typedef __attribute__((ext_vector_type(4))) float f4v;    // MFMA acc

#define MFMA_BF16 __builtin_amdgcn_mfma_f32_16x16x32_bf16

#define ASYNC_CP16(g, l)                                             \
  __builtin_amdgcn_global_load_lds(                                  \
      (const __attribute__((address_space(1))) void*)(g),            \
      (__attribute__((address_space(3))) void*)(l), 16, 0, 0)

// swizzled LDS element offset for (row, 16B-granule g) in a [*][64] tile
#define SWZ(row, g) ((row) * 64 + ((((g) ^ ((row) & 7))) * 8))

__device__ __forceinline__ unsigned short f2bf(float f) {
  union { float f; unsigned int u; } v; v.f = f;
  unsigned int r = (v.u + 0x7fffu + ((v.u >> 16) & 1u)) >> 16;  // RNE
  return (unsigned short)r;
}

__device__ __forceinline__ unsigned int pack_bf16(float a, float b) {
  union { __hip_bfloat162 h; unsigned int u; } cv;
  cv.h = __float22bfloat162_rn(make_float2(a, b));
  return cv.u;
}

// ---------------- 1) prep: f32->bf16 casts + weight transposes ---------------
// blocks 0..16383: cvt Xq/Xkv; blocks 16384..20479: wtrans of 4 weights.
__global__ __launch_bounds__(256) void prep_kernel(
    const float* __restrict__ s0, const float* __restrict__ s1,
    unsigned short* __restrict__ d0, unsigned short* __restrict__ d1,
    const float* __restrict__ W0, const float* __restrict__ W1,
    const float* __restrict__ W2, const float* __restrict__ W3,
    unsigned short* __restrict__ D0, unsigned short* __restrict__ D1,
    unsigned short* __restrict__ D2, unsigned short* __restrict__ D3) {
  int g = blockIdx.x;
  if (g < 16384) {
    const float* src = (g < 8192) ? s0 : s1;
    unsigned short* dst = (g < 8192) ? d0 : d1;
    int i = ((g & 8191) * 256 + threadIdx.x) * 4;
    float4 v = *(const float4*)(src + i);
    ushort4 o;
    o.x = f2bf(v.x); o.y = f2bf(v.y); o.z = f2bf(v.z); o.w = f2bf(v.w);
    *(ushort4*)(dst + i) = o;
  } else {
    int w = g - 16384;          // 0..4095
    int z = w >> 10;            // which weight
    int rem = w & 1023;
    const float* W = z == 0 ? W0 : z == 1 ? W1 : z == 2 ? W2 : W3;
    unsigned short* D = z == 0 ? D0 : z == 1 ? D1 : z == 2 ? D2 : D3;
    __shared__ float tile[32][33];
    int n0 = (rem & 31) * 32, k0 = (rem >> 5) * 32;
    int tx = threadIdx.x & 31, ty = threadIdx.x >> 5;  // 32 x 8
#pragma unroll
    for (int r = 0; r < 32; r += 8)
      tile[ty + r][tx] = W[(size_t)(k0 + ty + r) * 1024 + n0 + tx];
    __syncthreads();
#pragma unroll
    for (int r = 0; r < 32; r += 8)
      D[(size_t)(n0 + ty + r) * 1024 + k0 + tx] = f2bf(tile[tx][ty + r]);
  }
}

// ---------------- 2) projection GEMM (m97-style, swizzled, m-major) ---------
// grid (64=m, 8=n, 3=z).  128x128 tile, BK=64; 4 waves x 4x4 MFMA accs.
// z==0 (Q) additionally scales by 1/8 (softmax logit scale, exact in bf16).
__global__ __launch_bounds__(256) void proj_gemm(
    const unsigned short* __restrict__ XqBf, const unsigned short* __restrict__ XkvBf,
    const unsigned short* __restrict__ Wtq, const unsigned short* __restrict__ Wtk,
    const unsigned short* __restrict__ Wtv,
    unsigned short* __restrict__ Qb, unsigned short* __restrict__ Kb,
    unsigned short* __restrict__ Vt) {
  const int K = 1024;
  int z = blockIdx.z;
  const unsigned short* A  = (z == 0) ? XqBf : XkvBf;
  const unsigned short* Bt = (z == 0) ? Wtq : (z == 1) ? Wtk : Wtv;

  __shared__ __align__(16) unsigned short sA[128 * 64];
  __shared__ __align__(16) unsigned short sB[128 * 64];

  int tid = threadIdx.x;
  int lane = tid & 63, wave = tid >> 6;
  int quad = lane >> 4, l16 = lane & 15;
  int wm = wave & 1, wn = wave >> 1;
  int m_blk = blockIdx.x * 128, n_blk = blockIdx.y * 128;  // m-major!

  f4v acc[4][4] = {};
  int srow = tid >> 3, sg = (tid & 7) ^ (srow & 7);
  const unsigned short* gA = A + (size_t)(m_blk + srow) * K + sg * 8;
  const unsigned short* gB = Bt + (size_t)(n_blk + srow) * K + sg * 8;

  for (int k0 = 0; k0 < K; k0 += 64) {
#pragma unroll
    for (int i = 0; i < 4; ++i) {
      ASYNC_CP16(gA + (size_t)i * 32 * K + k0, &sA[i * 2048 + tid * 8]);
      ASYNC_CP16(gB + (size_t)i * 32 * K + k0, &sB[i * 2048 + tid * 8]);
    }
    __syncthreads();
#pragma unroll
    for (int ks = 0; ks < 64; ks += 32) {
      s8v af[4], bf[4];
#pragma unroll
      for (int mt = 0; mt < 4; ++mt)
        af[mt] = *(const s8v*)&sA[SWZ(wm * 64 + mt * 16 + l16, quad + (ks >> 3))];
#pragma unroll
      for (int nt = 0; nt < 4; ++nt)
        bf[nt] = *(const s8v*)&sB[SWZ(wn * 64 + nt * 16 + l16, quad + (ks >> 3))];
#pragma unroll
      for (int mt = 0; mt < 4; ++mt)
#pragma unroll
        for (int nt = 0; nt < 4; ++nt)
          acc[mt][nt] = MFMA_BF16(af[mt], bf[nt], acc[mt][nt], 0, 0, 0);
    }
    __syncthreads();
  }

  if (z < 2) {  // rotary epilogue -> Qb/Kb row-major [token][feat]
    unsigned short* Cb = (z == 0) ? Qb : Kb;
    float post = (z == 0) ? 0.125f : 1.0f;  // fold 1/sqrt(64) into Q (exact)
#pragma unroll
    for (int mt = 0; mt < 4; ++mt)
#pragma unroll
      for (int nt = 0; nt < 4; ++nt)
#pragma unroll
        for (int r = 0; r < 4; ++r) {
          int row = m_blk + wm * 64 + mt * 16 + quad * 4 + r;
          int col = n_blk + wn * 64 + nt * 16 + l16;
          float v = acc[mt][nt][r];
          float other = __shfl_xor(v, 1);  // pair partner: col^1 == lane^1
          int dh = col & 63;
          int tpos = row & 2047;
          float fi = (float)(dh >> 1) * (1.0f / 32.0f);
          float invf = __expf(-9.210340371976184f * fi);  // 10000^{-i/32}
          float ang = (float)tpos * invf;
          float s, c;
          __sincosf(ang, &s, &c);
          v = (dh & 1) ? (v * c + other * s) : (v * c - other * s);
          Cb[(size_t)row * 1024 + col] = f2bf(v * post);
        }
  } else {  // V: write transposed Vt[((b*16+h)*64+dh)][t], pack 4 consecutive t
#pragma unroll
    for (int mt = 0; mt < 4; ++mt)
#pragma unroll
      for (int nt = 0; nt < 4; ++nt) {
        int row0 = m_blk + wm * 64 + mt * 16 + quad * 4;  // t base (mult of 4)
        int col = n_blk + wn * 64 + nt * 16 + l16;        // feature
        int bb = row0 >> 11, t = row0 & 2047;
        int hh = col >> 6, dh = col & 63;
        ushort4 pk;
        pk.x = f2bf(acc[mt][nt][0]);
        pk.y = f2bf(acc[mt][nt][1]);
        pk.z = f2bf(acc[mt][nt][2]);
        pk.w = f2bf(acc[mt][nt][3]);
        *(ushort4*)&Vt[(((size_t)bb * 16 + hh) * 64 + dh) * 2048 + t] = pk;
      }
  }
}

// ---------------- 3) banded flash attention (S^T, 256-row q-blocks) ---------
// grid (T/256=8, H=16, B=4), 512 threads (8 waves); wave w owns rows
// t0+32w..+31 (2 f-frags).  S^T = K*Q^T: lane l16 = q row.
__global__ __launch_bounds__(512, 2) void attn_kernel(
    const unsigned short* __restrict__ Qb, const unsigned short* __restrict__ Kb,
    const unsigned short* __restrict__ Vt, unsigned short* __restrict__ Ab) {
  const int T = 2048;
  int t0 = blockIdx.x * 256;
  int h = blockIdx.y, b = blockIdx.z;
  int tid = threadIdx.x, lane = tid & 63, wave = tid >> 6;
  int quad = lane >> 4, l16 = lane & 15;

  __shared__ __align__(16) unsigned short sK[64][72];     // [key][d]
  __shared__ __align__(16) unsigned short sV[64][72];     // [d][key]
  __shared__ __align__(16) unsigned short sP[8][16][72];  // [wave][qrow][key]

  size_t base = ((size_t)b * T) * 1024 + (size_t)h * 64;
  size_t vbase = ((size_t)b * 16 + h) * 64 * 2048;
  int qlo = t0 + wave * 32;  // wave-uniform

  // Q B-fragments straight from global (B[k=quad*8+j][n=l16]); Q pre-scaled.
  s8v bq[2][2];
#pragma unroll
  for (int f = 0; f < 2; ++f) {
    const unsigned short* g = Qb + base + (size_t)(qlo + f * 16 + l16) * 1024;
    bq[f][0] = *(const s8v*)(g + quad * 8);
    bq[f][1] = *(const s8v*)(g + 32 + quad * 8);
  }

  f4v oacc[2][4] = {};
  float mrow[2] = {-1e30f, -1e30f}, lrow[2] = {0.0f, 0.0f};

  int kv_lo = max(0, t0 - 256);
  int kv_hi = min(T, t0 + 256 + 256);
  int ntiles = (kv_hi - kv_lo) >> 6;

  // staging with 512 threads: thread -> (row tid>>3, 16B granule tid&7)
  int srow = tid >> 3, sseg = (tid & 7) * 8;
  const unsigned short* gK = Kb + base + (size_t)(kv_lo + srow) * 1024 + sseg;
  const unsigned short* gV = Vt + vbase + (size_t)srow * 2048 + kv_lo + sseg;
  uint4 rk = *(const uint4*)gK;
  uint4 rv = *(const uint4*)gV;

  for (int it = 0; it < ntiles; ++it) {
    int kv0 = kv_lo + (it << 6);
    __syncthreads();  // previous tile's sK/sV reads complete
    *(uint4*)&sK[srow][sseg] = rk;
    *(uint4*)&sV[srow][sseg] = rv;
    __syncthreads();  // sK/sV ready
    if (it + 1 < ntiles) {  // register prefetch overlaps compute
      rk = *(const uint4*)(gK + (size_t)(it + 1) * 64 * 1024);
      rv = *(const uint4*)(gV + (it + 1) * 64);
    }
    // wave-level skip (barriers at loop top -> barrier-safe); every row of an
    // active tile has >=1 unmasked key (64/32 alignment).
    if (kv0 > qlo + 31 + 256 || kv0 + 63 < qlo - 256) continue;

#pragma unroll
    for (int f = 0; f < 2; ++f) {
      int qf = qlo + f * 16;     // wave-uniform
      int qg = qf + l16;         // this lane's q row
      // S^T = K * Q^T : A = K frag (m=key), B = Q frag (n=qrow)
      f4v sacc[4];
#pragma unroll
      for (int nt = 0; nt < 4; ++nt) {
        s8v ak0 = *(const s8v*)&sK[nt * 16 + l16][quad * 8];
        s8v ak1 = *(const s8v*)&sK[nt * 16 + l16][32 + quad * 8];
        f4v zz = {};
        zz = MFMA_BF16(ak0, bq[f][0], zz, 0, 0, 0);
        sacc[nt] = MFMA_BF16(ak1, bq[f][1], zz, 0, 0, 0);
      }
      // mask only when the tile isn't fully inside the band (wave-uniform)
      bool full = (kv0 >= qf - 241) && (kv0 <= qf + 193);
      if (!full) {
#pragma unroll
        for (int nt = 0; nt < 4; ++nt) {
          int kg = kv0 + nt * 16 + quad * 4;
#pragma unroll
          for (int r = 0; r < 4; ++r) {
            int d = qg - (kg + r);
            if (d > 256 || d < -256) sacc[nt][r] = -1e30f;
          }
        }
      }
      // row max: in-lane over 16 + cross-quad (2 shfls)
      float mymax = sacc[0][0];
#pragma unroll
      for (int nt = 0; nt < 4; ++nt)
#pragma unroll
        for (int r = 0; r < 4; ++r) mymax = fmaxf(mymax, sacc[nt][r]);
      mymax = fmaxf(mymax, __shfl_xor(mymax, 16));
      mymax = fmaxf(mymax, __shfl_xor(mymax, 32));

      float mn = fmaxf(mrow[f], mymax);
      float alpha = __expf(mrow[f] - mn);
      mrow[f] = mn;

      float mysum = 0.0f;
#pragma unroll
      for (int nt = 0; nt < 4; ++nt) {
        float e0 = __expf(sacc[nt][0] - mn);
        float e1 = __expf(sacc[nt][1] - mn);
        float e2 = __expf(sacc[nt][2] - mn);
        float e3 = __expf(sacc[nt][3] - mn);
        mysum += (e0 + e1) + (e2 + e3);
        *(uint2*)&sP[wave][l16][nt * 16 + quad * 4] =
            make_uint2(pack_bf16(e0, e1), pack_bf16(e2, e3));
      }
      mysum += __shfl_xor(mysum, 16);
      mysum += __shfl_xor(mysum, 32);
      lrow[f] = lrow[f] * alpha + mysum;

      // P^T B-frags (B[k=key][n=qrow]) from this wave's sP region
      s8v pb0 = *(const s8v*)&sP[wave][l16][quad * 8];
      s8v pb1 = *(const s8v*)&sP[wave][l16][32 + quad * 8];

      // O^T += V^T * P^T : A = V^T frag (m=d), B = P^T
#pragma unroll
      for (int dt = 0; dt < 4; ++dt) {
        s8v av0 = *(const s8v*)&sV[dt * 16 + l16][quad * 8];
        s8v av1 = *(const s8v*)&sV[dt * 16 + l16][32 + quad * 8];
        f4v o = oacc[f][dt];
#pragma unroll
        for (int r = 0; r < 4; ++r) o[r] *= alpha;
        o = MFMA_BF16(av0, pb0, o, 0, 0, 0);
        oacc[f][dt] = MFMA_BF16(av1, pb1, o, 0, 0, 0);
      }
    }
  }

  // normalize + store: O^T C-layout -> lane has q-row l16, d = dt*16+quad*4+r
#pragma unroll
  for (int f = 0; f < 2; ++f) {
    float inv = 1.0f / lrow[f];
    size_t rowoff = base + (size_t)(qlo + f * 16 + l16) * 1024;
#pragma unroll
    for (int dt = 0; dt < 4; ++dt) {
      float o0 = oacc[f][dt][0] * inv, o1 = oacc[f][dt][1] * inv;
      float o2 = oacc[f][dt][2] * inv, o3 = oacc[f][dt][3] * inv;
      *(uint2*)&Ab[rowoff + dt * 16 + quad * 4] =
          make_uint2(pack_bf16(o0, o1), pack_bf16(o2, o3));
    }
  }
}

// ---------------- 4) output GEMM (swizzled, m-major): f32 out ---------------
__global__ __launch_bounds__(256) void out_gemm(
    const unsigned short* __restrict__ A, const unsigned short* __restrict__ Bt,
    float* __restrict__ C) {
  const int K = 1024;
  __shared__ __align__(16) unsigned short sA[128 * 64];
  __shared__ __align__(16) unsigned short sB[128 * 64];

  int tid = threadIdx.x;
  int lane = tid & 63, wave = tid >> 6;
  int quad = lane >> 4, l16 = lane & 15;
  int wm = wave & 1, wn = wave >> 1;
  int m_blk = blockIdx.x * 128, n_blk = blockIdx.y * 128;  // m-major

  f4v acc[4][4] = {};
  int srow = tid >> 3, sg = (tid & 7) ^ (srow & 7);
  const unsigned short* gA = A + (size_t)(m_blk + srow) * K + sg * 8;
  const unsigned short* gB = Bt + (size_t)(n_blk + srow) * K + sg * 8;

  for (int k0 = 0; k0 < K; k0 += 64) {
#pragma unroll
    for (int i = 0; i < 4; ++i) {
      ASYNC_CP16(gA + (size_t)i * 32 * K + k0, &sA[i * 2048 + tid * 8]);
      ASYNC_CP16(gB + (size_t)i * 32 * K + k0, &sB[i * 2048 + tid * 8]);
    }
    __syncthreads();
#pragma unroll
    for (int ks = 0; ks < 64; ks += 32) {
      s8v af[4], bf[4];
#pragma unroll
      for (int mt = 0; mt < 4; ++mt)
        af[mt] = *(const s8v*)&sA[SWZ(wm * 64 + mt * 16 + l16, quad + (ks >> 3))];
#pragma unroll
      for (int nt = 0; nt < 4; ++nt)
        bf[nt] = *(const s8v*)&sB[SWZ(wn * 64 + nt * 16 + l16, quad + (ks >> 3))];
#pragma unroll
      for (int mt = 0; mt < 4; ++mt)
#pragma unroll
        for (int nt = 0; nt < 4; ++nt)
          acc[mt][nt] = MFMA_BF16(af[mt], bf[nt], acc[mt][nt], 0, 0, 0);
    }
    __syncthreads();
  }

#pragma unroll
  for (int mt = 0; mt < 4; ++mt)
#pragma unroll
    for (int nt = 0; nt < 4; ++nt)
#pragma unroll
      for (int r = 0; r < 4; ++r) {
        int row = m_blk + wm * 64 + mt * 16 + quad * 4 + r;
        int col = n_blk + wn * 64 + nt * 16 + l16;
        C[(size_t)row * 1024 + col] = acc[mt][nt][r];
      }
}

// ---------------- launch -----------------------------------------------------
extern "C" void kernel_launch(void* const* d_in, const int* in_sizes, int n_in,
                              void* d_out, int out_size, void* d_ws, size_t ws_size,
                              hipStream_t stream) {
  const float* Xq  = (const float*)d_in[0];
  const float* Xkv = (const float*)d_in[1];
  const float* Wq  = (const float*)d_in[2];
  const float* Wk  = (const float*)d_in[3];
  const float* Wv  = (const float*)d_in[4];
  const float* Wo  = (const float*)d_in[5];
  float* out = (float*)d_out;

  char* ws = (char*)d_ws;
  const size_t MB = 1ull << 20;
  unsigned short* XqBf  = (unsigned short*)(ws + 0 * MB);   // 16 MiB
  unsigned short* XkvBf = (unsigned short*)(ws + 16 * MB);  // 16 MiB
  unsigned short* Wtq   = (unsigned short*)(ws + 32 * MB);  // 2 MiB each
  unsigned short* Wtk   = (unsigned short*)(ws + 34 * MB);
  unsigned short* Wtv   = (unsigned short*)(ws + 36 * MB);
  unsigned short* Wto   = (unsigned short*)(ws + 38 * MB);
  unsigned short* Qb    = (unsigned short*)(ws + 40 * MB);  // 16 MiB
  unsigned short* Kb    = (unsigned short*)(ws + 56 * MB);  // 16 MiB
  unsigned short* Vt    = (unsigned short*)(ws + 72 * MB);  // 16 MiB (transposed V)
  unsigned short* Ab    = XqBf;  // reuse: XqBf dead after proj_gemm

  prep_kernel<<<20480, 256, 0, stream>>>(Xq, Xkv, XqBf, XkvBf,
                                         Wq, Wk, Wv, Wo, Wtq, Wtk, Wtv, Wto);
  proj_gemm<<<dim3(64, 8, 3), 256, 0, stream>>>(XqBf, XkvBf, Wtq, Wtk, Wtv, Qb, Kb, Vt);
  attn_kernel<<<dim3(8, 16, 4), 512, 0, stream>>>(Qb, Kb, Vt, Ab);
  out_gemm<<<dim3(64, 8), 256, 0, stream>>>(Ab, Wto, out);
}